// Round 5
// baseline (742.694 us; speedup 1.0000x reference)
//
#include <hip/hip_runtime.h>
#include <hip/hip_bf16.h>

// SGA_75531294867605 — GRU x2 -> cos-sim topK concept graph -> softmax attention head.
// R14: MEASUREMENT ROUND. Four rounds (R10-R13) of structurally different pipelines
//      all land at 429-433us while bottom-up arithmetic predicts ~260us; the top-5
//      counter view is blind below gru's 122us. This round inflates every
//      un-measured middle kernel x4 via an idempotent rep-loop (outputs bit-identical;
//      atomics guarded to last rep): Δtotal = 3*Σ(middle), and any kernel >31us true
//      cost appears in top-5 at 4x, identifying the hidden elephant. De-inflate next round.

typedef float f32x4 __attribute__((ext_vector_type(4)));
typedef short s16x8 __attribute__((ext_vector_type(8)));
typedef unsigned short u16;
typedef unsigned long long u64;

#define REPS 4

#define DEVFN static __device__ __forceinline__

DEVFN u16 f2bf(float f) {
  union { float f; unsigned u; } v; v.f = f;
  return (u16)((v.u + 0x7FFFu + ((v.u >> 16) & 1u)) >> 16);  // RNE
}

DEVFN unsigned f2bf_pk(float lo, float hi) {   // low16=bf16(lo), high16=bf16(hi)
  union { __hip_bfloat162 h; unsigned u; } p;
  p.h = __float22bfloat162_rn(make_float2(lo, hi));
  return p.u;
}

DEVFN f32x4 mfma16(s16x8 a, s16x8 b, f32x4 c) {
  return __builtin_amdgcn_mfma_f32_16x16x32_bf16(a, b, c, 0, 0, 0);
}

DEVFN float sigmf(float x) { return __builtin_amdgcn_rcpf(1.f + __expf(-x)); }
DEVFN float tanhf_fast(float x) {
  float e = __expf(2.f * x);
  return 1.f - 2.f * __builtin_amdgcn_rcpf(e + 1.f);
}
DEVFN float lrelu(float v) { return v > 0.f ? v : 0.2f * v; }

// ---------------------------------------------------------------- all-weights fp32->bf16 (+ counter zeroing)
__global__ void cvt_all(const float* __restrict__ w0, const float* __restrict__ w1,
                        const float* __restrict__ w2, const float* __restrict__ w3,
                        const float* __restrict__ w4, const float* __restrict__ w5,
                        const float* __restrict__ w6, const float* __restrict__ w7,
                        u16* __restrict__ dst, int* __restrict__ zbuf) {
  int i = blockIdx.x * 256 + threadIdx.x;
  if (i >= 225280) return;
  if (i < 12288) zbuf[i] = 0;          // cnt[4096] + touched[4096] + colsum[4096]
  float v;
  if      (i < 12288)  v = w0[i];
  else if (i < 61440)  v = w1[i - 12288];
  else if (i < 110592) v = w2[i - 61440];
  else if (i < 159744) v = w3[i - 110592];
  else if (i < 176128) v = w4[i - 159744];
  else if (i < 192512) v = w5[i - 176128];
  else if (i < 208896) v = w6[i - 192512];
  else                 v = w7[i - 208896];
  dst[i] = f2bf(v);
}

// ---------------------------------------------------------------- fused 2-layer GRU (+ norms + bf16 g)
__launch_bounds__(512, 1)
__global__ void gru_fused(const float* __restrict__ x,
                          const u16* __restrict__ Wih0, const u16* __restrict__ Whh0,
                          const float* __restrict__ bih0, const float* __restrict__ bhh0,
                          const u16* __restrict__ Wih1, const u16* __restrict__ Whh1,
                          const float* __restrict__ bih1, const float* __restrict__ bhh1,
                          float* __restrict__ g_out, u16* __restrict__ gbf,
                          float* __restrict__ rn)
{
  const int tid  = threadIdx.x;
  const int w    = tid >> 6;
  const int l    = tid & 63;
  const int quad = l >> 4;
  const int l16  = l & 15;
  const int r0   = blockIdx.x * 16;
  const int c    = w * 16 + l16;

  __shared__ u16 sh_x[64][16 * 40];      // 81,920 B : all 64 timesteps, bf16
  __shared__ u16 sh_h0[2][16 * 136];     //  8,704 B
  __shared__ u16 sh_h1[2][16 * 136];     //  8,704 B
  __shared__ float red16[16][8];         //    512 B : row-norm cross-wave partials

  s16x8 B0ih[3];
  s16x8 B0hh[3][4];
  s16x8 B1ih[3][4];
  s16x8 B1hh[3][4];
  float brz0[2], bin0, bhn0, brz1[2], bin1, bhn1;
  {
    int j0g = c, j1g = 128 + c, j2g = 256 + c;
    brz0[0] = bih0[j0g] + bhh0[j0g];  brz0[1] = bih0[j1g] + bhh0[j1g];
    bin0 = bih0[j2g];  bhn0 = bhh0[j2g];
    brz1[0] = bih1[j0g] + bhh1[j0g];  brz1[1] = bih1[j1g] + bhh1[j1g];
    bin1 = bih1[j2g];  bhn1 = bhh1[j2g];
  }
#pragma unroll
  for (int g = 0; g < 3; ++g) {
    int j = g * 128 + c;
    B0ih[g] = *(const s16x8*)(Wih0 + j * 32 + quad * 8);
#pragma unroll
    for (int kk = 0; kk < 4; ++kk) {
      B0hh[g][kk] = *(const s16x8*)(Whh0 + j * 128 + kk * 32 + quad * 8);
      B1ih[g][kk] = *(const s16x8*)(Wih1 + j * 128 + kk * 32 + quad * 8);
      B1hh[g][kk] = *(const s16x8*)(Whh1 + j * 128 + kk * 32 + quad * 8);
    }
  }
  float h0reg[4] = {0.f, 0.f, 0.f, 0.f};
  float h1reg[4] = {0.f, 0.f, 0.f, 0.f};
  for (int idx = tid; idx < 16 * 136; idx += 512) sh_h1[0][idx] = 0;

  // ---- preload the whole x tile (16 rows x 64 t x 32 f) -> LDS bf16, coalesced
  for (int q = tid; q < 8192; q += 512) {
    int r  = q >> 9;           // 0..15
    int t  = (q >> 3) & 63;    // 0..63
    int c4 = (q & 7) * 4;      // 0,4,...,28
    float4 v = *(const float4*)(x + (size_t)(r0 + r) * 2048 + t * 32 + c4);
    unsigned p0 = f2bf_pk(v.x, v.y);
    unsigned p1 = f2bf_pk(v.z, v.w);
    *(uint2*)(&sh_x[t][r * 40 + c4]) = make_uint2(p0, p1);
  }
  __syncthreads();

  const f32x4 zz4 = {0.f, 0.f, 0.f, 0.f};
  // ---- prologue: h0(0) from x(0), h0(-1)=0
  {
    s16x8 ax = *(const s16x8*)(sh_x[0] + l16 * 40 + quad * 8);
    f32x4 ai[3];
#pragma unroll
    for (int g = 0; g < 3; ++g) ai[g] = mfma16(ax, B0ih[g], zz4);
#pragma unroll
    for (int i = 0; i < 4; i += 2) {
      float hn[2];
#pragma unroll
      for (int q = 0; q < 2; ++q) {
        int ii = i + q;
        float rr = sigmf(ai[0][ii] + brz0[0]);
        float zg = sigmf(ai[1][ii] + brz0[1]);
        float nn = tanhf_fast(ai[2][ii] + bin0 + rr * bhn0);
        hn[q] = nn - zg * nn;
        h0reg[ii] = hn[q];
      }
      unsigned pk = f2bf_pk(hn[0], hn[1]);
      int m = quad * 4 + i;
      sh_h0[0][m * 136 + c]       = (u16)pk;
      sh_h0[0][(m + 1) * 136 + c] = (u16)(pk >> 16);
    }
  }

  // ---- main: phase t computes L1(t) + L0(t+1); unrolled x2, compile-time parity.
#define GRU_STEP(T, CUR, NXT)                                                     \
  {                                                                               \
    __syncthreads();                                                              \
    s16x8 ah0[4], ah1[4];                                                         \
    _Pragma("unroll")                                                             \
    for (int kk = 0; kk < 4; ++kk) {                                              \
      ah0[kk] = *(const s16x8*)(sh_h0[CUR] + l16 * 136 + kk * 32 + quad * 8);     \
      ah1[kk] = *(const s16x8*)(sh_h1[CUR] + l16 * 136 + kk * 32 + quad * 8);     \
    }                                                                             \
    s16x8 ax = *(const s16x8*)(sh_x[(T) + 1] + l16 * 40 + quad * 8);              \
    f32x4 r1a, z1a, ni1, nh1, r0a, z0a, ni0, nh0;                                 \
    r1a = mfma16(ah0[0], B1ih[0][0], zz4);                                        \
    z1a = mfma16(ah0[0], B1ih[1][0], zz4);                                        \
    ni1 = mfma16(ah0[0], B1ih[2][0], zz4);                                        \
    nh1 = mfma16(ah1[0], B1hh[2][0], zz4);                                        \
    r0a = mfma16(ax, B0ih[0], zz4);                                               \
    z0a = mfma16(ax, B0ih[1], zz4);                                               \
    ni0 = mfma16(ax, B0ih[2], zz4);                                               \
    nh0 = mfma16(ah0[0], B0hh[2][0], zz4);                                        \
    _Pragma("unroll")                                                             \
    for (int kk = 1; kk < 4; ++kk) {                                              \
      r1a = mfma16(ah0[kk], B1ih[0][kk], r1a);                                    \
      z1a = mfma16(ah0[kk], B1ih[1][kk], z1a);                                    \
      ni1 = mfma16(ah0[kk], B1ih[2][kk], ni1);                                    \
      nh1 = mfma16(ah1[kk], B1hh[2][kk], nh1);                                    \
      nh0 = mfma16(ah0[kk], B0hh[2][kk], nh0);                                    \
    }                                                                             \
    _Pragma("unroll")                                                             \
    for (int kk = 0; kk < 4; ++kk) {                                              \
      r1a = mfma16(ah1[kk], B1hh[0][kk], r1a);                                    \
      z1a = mfma16(ah1[kk], B1hh[1][kk], z1a);                                    \
      r0a = mfma16(ah0[kk], B0hh[0][kk], r0a);                                    \
      z0a = mfma16(ah0[kk], B0hh[1][kk], z0a);                                    \
    }                                                                             \
    _Pragma("unroll")                                                             \
    for (int i = 0; i < 4; i += 2) {                                              \
      float hn[2];                                                                \
      _Pragma("unroll")                                                           \
      for (int q = 0; q < 2; ++q) {                                               \
        int ii = i + q;                                                           \
        float rr = sigmf(r1a[ii] + brz1[0]);                                      \
        float zg = sigmf(z1a[ii] + brz1[1]);                                      \
        float nn = tanhf_fast(ni1[ii] + bin1 + rr * (nh1[ii] + bhn1));            \
        hn[q] = nn + zg * (h1reg[ii] - nn);                                       \
        h1reg[ii] = hn[q];                                                        \
      }                                                                           \
      unsigned pk = f2bf_pk(hn[0], hn[1]);                                        \
      int m = quad * 4 + i;                                                       \
      sh_h1[NXT][m * 136 + c]       = (u16)pk;                                    \
      sh_h1[NXT][(m + 1) * 136 + c] = (u16)(pk >> 16);                            \
    }                                                                             \
    _Pragma("unroll")                                                             \
    for (int i = 0; i < 4; i += 2) {                                              \
      float hn[2];                                                                \
      _Pragma("unroll")                                                           \
      for (int q = 0; q < 2; ++q) {                                               \
        int ii = i + q;                                                           \
        float rr = sigmf(r0a[ii] + brz0[0]);                                      \
        float zg = sigmf(z0a[ii] + brz0[1]);                                      \
        float nn = tanhf_fast(ni0[ii] + bin0 + rr * (nh0[ii] + bhn0));            \
        hn[q] = nn + zg * (h0reg[ii] - nn);                                       \
        h0reg[ii] = hn[q];                                                        \
      }                                                                           \
      unsigned pk = f2bf_pk(hn[0], hn[1]);                                        \
      int m = quad * 4 + i;                                                       \
      sh_h0[NXT][m * 136 + c]       = (u16)pk;                                    \
      sh_h0[NXT][(m + 1) * 136 + c] = (u16)(pk >> 16);                            \
    }                                                                             \
  }

  for (int t2 = 0; t2 < 31; ++t2) {
    int t = t2 * 2;
    GRU_STEP(t, 0, 1);
    GRU_STEP(t + 1, 1, 0);
  }
  GRU_STEP(62, 0, 1);   // t = 62
#undef GRU_STEP

  // ---- epilogue: L1(63); h0(63)@buf1, h1(62)@buf1. Fused: g fp32 + g bf16 + row norms.
  __syncthreads();
  {
    s16x8 ah0[4], ah1[4];
#pragma unroll
    for (int kk = 0; kk < 4; ++kk) {
      ah0[kk] = *(const s16x8*)(sh_h0[1] + l16 * 136 + kk * 32 + quad * 8);
      ah1[kk] = *(const s16x8*)(sh_h1[1] + l16 * 136 + kk * 32 + quad * 8);
    }
    f32x4 r1a, z1a, ni1, nh1;
    r1a = mfma16(ah0[0], B1ih[0][0], zz4);
    z1a = mfma16(ah0[0], B1ih[1][0], zz4);
    ni1 = mfma16(ah0[0], B1ih[2][0], zz4);
    nh1 = mfma16(ah1[0], B1hh[2][0], zz4);
#pragma unroll
    for (int kk = 1; kk < 4; ++kk) {
      r1a = mfma16(ah0[kk], B1ih[0][kk], r1a);
      z1a = mfma16(ah0[kk], B1ih[1][kk], z1a);
      ni1 = mfma16(ah0[kk], B1ih[2][kk], ni1);
      nh1 = mfma16(ah1[kk], B1hh[2][kk], nh1);
    }
#pragma unroll
    for (int kk = 0; kk < 4; ++kk) {
      r1a = mfma16(ah1[kk], B1hh[0][kk], r1a);
      z1a = mfma16(ah1[kk], B1hh[1][kk], z1a);
    }
    float hv[4];
#pragma unroll
    for (int i = 0; i < 4; ++i) {
      int m = quad * 4 + i;
      float rr = sigmf(r1a[i] + brz1[0]);
      float zg = sigmf(z1a[i] + brz1[1]);
      float nn = tanhf_fast(ni1[i] + bin1 + rr * (nh1[i] + bhn1));
      float hnew = nn + zg * (h1reg[i] - nn);
      hv[i] = hnew;
      g_out[(size_t)(r0 + m) * 128 + c] = hnew;
      gbf[(size_t)(r0 + m) * 128 + c]   = f2bf(hnew);
    }
    // row-norm partials: reduce over the 16 l16-lanes of this quad (cols of this wave)
#pragma unroll
    for (int i = 0; i < 4; ++i) {
      float s = hv[i] * hv[i];
      s += __shfl_xor(s, 1);
      s += __shfl_xor(s, 2);
      s += __shfl_xor(s, 4);
      s += __shfl_xor(s, 8);
      if (l16 == 0) red16[quad * 4 + i][w] = s;
    }
  }
  __syncthreads();
  if (tid < 16) {
    float s = 0.f;
#pragma unroll
    for (int k = 0; k < 8; ++k) s += red16[tid][k];
    rn[r0 + tid] = (s == 0.f) ? 0.f : rsqrtf(s);
  }
}

// ---------------------------------------------------------------- cos-sim GEMM  [INFLATED x4]
template<int MODE>
__launch_bounds__(256, 1)
__global__ void cos_gemm(const u16* __restrict__ A, const u16* __restrict__ B,
                         const float* __restrict__ rnA, const float* __restrict__ rnB,
                         float* __restrict__ C, u16* __restrict__ E,
                         float* __restrict__ colsum)
{
  __shared__ u16 shA[128 * 136];
  __shared__ u16 shB[128 * 136];
  const int tid = threadIdx.x;
  const int l = tid & 63, wv = tid >> 6;
  const int quad = l >> 4, l16 = l & 15;
  const int i0 = blockIdx.y * 128, j0 = blockIdx.x * 128;
  const int wm = wv >> 1, wn = wv & 1;
  const f32x4 zz4 = {0.f, 0.f, 0.f, 0.f};

  for (int rep = 0; rep < REPS; ++rep) {
    __syncthreads();
    {
      int r = tid >> 1, half = tid & 1;
      const int4* sa = (const int4*)(A + (size_t)(i0 + r) * 128 + half * 64);
      int4* da = (int4*)(shA + r * 136 + half * 64);
      const int4* sb = (const int4*)(B + (size_t)(j0 + r) * 128 + half * 64);
      int4* db = (int4*)(shB + r * 136 + half * 64);
#pragma unroll
      for (int q = 0; q < 8; ++q) { da[q] = sa[q]; db[q] = sb[q]; }
    }
    __syncthreads();
    f32x4 acc[4][4];
#pragma unroll
    for (int a = 0; a < 4; ++a)
#pragma unroll
      for (int b = 0; b < 4; ++b) acc[a][b] = zz4;
#pragma unroll
    for (int kk = 0; kk < 4; ++kk) {
      s16x8 af[4], bfr[4];
#pragma unroll
      for (int mt = 0; mt < 4; ++mt)
        af[mt] = *(const s16x8*)(shA + (wm * 64 + mt * 16 + l16) * 136 + kk * 32 + quad * 8);
#pragma unroll
      for (int nt = 0; nt < 4; ++nt)
        bfr[nt] = *(const s16x8*)(shB + (wn * 64 + nt * 16 + l16) * 136 + kk * 32 + quad * 8);
#pragma unroll
      for (int mt = 0; mt < 4; ++mt)
#pragma unroll
        for (int nt = 0; nt < 4; ++nt) acc[mt][nt] = mfma16(af[mt], bfr[nt], acc[mt][nt]);
    }
    float ra[4][4];
#pragma unroll
    for (int mt = 0; mt < 4; ++mt)
#pragma unroll
      for (int i = 0; i < 4; ++i) ra[mt][i] = rnA[i0 + wm * 64 + mt * 16 + quad * 4 + i];
#pragma unroll
    for (int nt = 0; nt < 4; ++nt) {
      int col = j0 + wn * 64 + nt * 16 + l16;
      float rb = rnB[col];
      float psum = 0.f;
#pragma unroll
      for (int mt = 0; mt < 4; ++mt)
#pragma unroll
        for (int i = 0; i < 4; ++i) {
          int row = i0 + wm * 64 + mt * 16 + quad * 4 + i;
          float v = acc[mt][nt][i] * ra[mt][i] * rb;
          if constexpr (MODE == 0) {
            C[(size_t)row * 4096 + col] = v;
          } else {
            float e = __expf(v);
            E[(size_t)row * 4096 + col] = f2bf(e);
            psum += e;
          }
        }
      if constexpr (MODE == 1) {
        psum += __shfl_xor(psum, 16);
        psum += __shfl_xor(psum, 32);
        if (quad == 0 && rep == REPS - 1) atomicAdd(colsum + col, psum);
      }
    }
  }
}

// ---------------------------------------------------------------- topK select  [INFLATED x4]
__launch_bounds__(256, 1)
__global__ void topk_select(const float* __restrict__ sim,
                            int* __restrict__ gselj, float* __restrict__ gselv,
                            int* __restrict__ cnt, int* __restrict__ touched)
{
  __shared__ unsigned hist[2048];
  __shared__ u64 cand[3072];
  __shared__ int selj[20];
  __shared__ unsigned ws4[4];
  __shared__ unsigned wmin4[4], wmax4[4];
  __shared__ int shb, shcnt;
  const int tid = threadIdx.x;
  const int row = blockIdx.x;
  const int l = tid & 63, wv = tid >> 6;

  for (int rep = 0; rep < REPS; ++rep) {
    __syncthreads();
    for (int i = tid; i < 2048; i += 256) hist[i] = 0;
    if (tid == 0) shcnt = 0;

    unsigned key[4][4];
    unsigned lmin = 0xFFFFFFFFu, lmax = 0u;
#pragma unroll
    for (int q = 0; q < 4; ++q) {
      int e0 = (q * 256 + tid) * 4;
      float4 v = *(const float4*)(sim + (size_t)row * 4096 + e0);
      key[q][0] = (e0 + 0 == row) ? 0u : (__float_as_uint(v.x) & 0x7FFFFFFFu);
      key[q][1] = (e0 + 1 == row) ? 0u : (__float_as_uint(v.y) & 0x7FFFFFFFu);
      key[q][2] = (e0 + 2 == row) ? 0u : (__float_as_uint(v.z) & 0x7FFFFFFFu);
      key[q][3] = (e0 + 3 == row) ? 0u : (__float_as_uint(v.w) & 0x7FFFFFFFu);
#pragma unroll
      for (int c = 0; c < 4; ++c) {
        unsigned k = key[q][c];
        lmin = k < lmin ? k : lmin;
        lmax = k > lmax ? k : lmax;
      }
    }
#pragma unroll
    for (int off = 1; off < 64; off <<= 1) {
      unsigned om = __shfl_xor(lmin, off); lmin = om < lmin ? om : lmin;
      unsigned ox = __shfl_xor(lmax, off); lmax = ox > lmax ? ox : lmax;
    }
    if (l == 0) { wmin4[wv] = lmin; wmax4[wv] = lmax; }
    __syncthreads();
    const unsigned kmin = min(min(wmin4[0], wmin4[1]), min(wmin4[2], wmin4[3]));
    const unsigned kmax = max(max(wmax4[0], wmax4[1]), max(wmax4[2], wmax4[3]));
    const float binscale = (kmax > kmin) ? (2047.0f / (float)(kmax - kmin)) : 0.0f;

#define BIN_OF(k) ((int)((float)((k) - kmin) * binscale))

#pragma unroll
    for (int q = 0; q < 4; ++q)
#pragma unroll
      for (int c = 0; c < 4; ++c) {
        int bin = BIN_OF(key[q][c]); if (bin > 2047) bin = 2047;
        atomicAdd(&hist[bin], 1u);
      }
    __syncthreads();

    unsigned s = 0;
#pragma unroll
    for (int j = 0; j < 8; ++j) s += hist[tid * 8 + j];
    unsigned r = s;
#pragma unroll
    for (int off = 1; off < 64; off <<= 1) {
      unsigned o = __shfl_down(r, off);
      if (l + off < 64) r += o;
    }
    if (l == 0) ws4[wv] = r;
    __syncthreads();
    unsigned upper = 0;
    for (int q = wv + 1; q < 4; ++q) upper += ws4[q];
    unsigned excl = upper + (r - s);
    if (excl < 20u && excl + s >= 20u) {
      unsigned cum = excl;
      for (int j = 7; j >= 0; --j) {
        cum += hist[tid * 8 + j];
        if (cum >= 20u) { shb = tid * 8 + j; break; }
      }
    }
    __syncthreads();
    const int b = shb;

#pragma unroll
    for (int q = 0; q < 4; ++q) {
      int e0 = (q * 256 + tid) * 4;
#pragma unroll
      for (int c = 0; c < 4; ++c) {
        int bin = BIN_OF(key[q][c]); if (bin > 2047) bin = 2047;
        if (bin >= b) {
          int p = atomicAdd(&shcnt, 1);
          if (p < 3072) cand[p] = ((u64)key[q][c] << 32) | (u64)(4095 - (e0 + c));
        }
      }
    }
#undef BIN_OF
    __syncthreads();
    const int C = (shcnt < 3072) ? shcnt : 3072;

    if (wv == 0) {
      if (C <= 64) {
        u64 mykey = (l < C) ? cand[l] : 0ull;
        for (int it = 0; it < 20; ++it) {
          u64 m = mykey;
#pragma unroll
          for (int off = 1; off < 64; off <<= 1) {
            u64 o = __shfl_xor(m, off);
            if (o > m) m = o;
          }
          if (mykey == m) mykey = 0ull;
          if (l == 0) selj[it] = 4095 - (int)(m & 0xFFFull);
        }
      } else {
        for (int it = 0; it < 20; ++it) {
          u64 best = 0ull; int bpos = -1;
          for (int p = l; p < C; p += 64) {
            u64 cv = cand[p];
            if (cv > best) { best = cv; bpos = p; }
          }
          u64 mine = best;
#pragma unroll
          for (int off = 1; off < 64; off <<= 1) {
            u64 o = __shfl_xor(best, off);
            if (o > best) best = o;
          }
          if (mine == best && bpos >= 0 && best != 0ull) cand[bpos] = 0ull;
          if (l == 0) selj[it] = 4095 - (int)(best & 0xFFFull);
        }
      }
    }
  }
  __syncthreads();
  if (tid < 20) {
    int idx = selj[tid];
    float sv = (idx == row) ? 0.f : sim[(size_t)row * 4096 + idx];
    gselj[row * 20 + tid] = idx;
    gselv[row * 20 + tid] = sv;
    atomicAdd(&cnt[idx], 1);
    if (sv != 0.f) atomicOr(touched + idx, 1);
  }
}

// ---------------------------------------------------------------- exclusive scan of cnt[4096]  [INFLATED x4]
__launch_bounds__(1024, 1)
__global__ void scan4096(const int* __restrict__ cnt, int* __restrict__ offs,
                         int* __restrict__ cur)
{
  __shared__ int wsum[16];
  const int t = threadIdx.x, l = t & 63, wv = t >> 6;
  for (int rep = 0; rep < REPS; ++rep) {
    __syncthreads();
    int4 c = ((const int4*)cnt)[t];
    int s = c.x + c.y + c.z + c.w;
    int ps = s;
#pragma unroll
    for (int off = 1; off < 64; off <<= 1) {
      int o = __shfl_up(ps, off);
      if (l >= off) ps += o;
    }
    if (l == 63) wsum[wv] = ps;
    __syncthreads();
    if (t == 0) {
      int a = 0;
#pragma unroll
      for (int q = 0; q < 16; ++q) { int x = wsum[q]; wsum[q] = a; a += x; }
    }
    __syncthreads();
    int base = wsum[wv] + (ps - s);
    int4 o4;
    o4.x = base; o4.y = o4.x + c.x; o4.z = o4.y + c.y; o4.w = o4.z + c.z;
    ((int4*)offs)[t] = o4;
    ((int4*)cur)[t] = o4;
  }
}

// ---------------------------------------------------------------- CSR entry scatter
__global__ void scatter_entries(const int* __restrict__ gselj, const float* __restrict__ gselv,
                                int* __restrict__ cur, int* __restrict__ eid,
                                float* __restrict__ ev)
{
  unsigned idx = blockIdx.x * 256 + threadIdx.x;
  unsigned row = idx / 20u;
  int j = gselj[idx]; float v = gselv[idx];
  int pos = atomicAdd(&cur[j], 1);
  eid[pos] = (int)row; ev[pos] = v;
}

// ---------------------------------------------------------------- concept gather + cf fused  [INFLATED x4]
__launch_bounds__(1024, 1)
__global__ void concept_cf(const int* __restrict__ offs, const int* __restrict__ cnt,
                           const int* __restrict__ eid, const float* __restrict__ ev,
                           const float* __restrict__ g, const float* __restrict__ rng,
                           const int* __restrict__ touched,
                           const float* __restrict__ Whc, const float* __restrict__ bhc,
                           float* __restrict__ cf, u16* __restrict__ cfbf,
                           float* __restrict__ rncf)
{
  __shared__ float part[8][128];
  __shared__ float shc[128];
  __shared__ float svalid;
  const int tid = threadIdx.x;
  const int d = tid & 127, grp = tid >> 7;
  const int j = blockIdx.x;
  const int off = offs[j], n = cnt[j];

  for (int rep = 0; rep < REPS; ++rep) {
    __syncthreads();
    float acc = 0.f;
    {
      int p = grp;
      if (p < n) {
        int i = eid[off + p]; float v = ev[off + p];
        for (p += 8; p < n; p += 8) {
          int i2 = eid[off + p]; float v2 = ev[off + p];
          acc += v * g[(size_t)i * 128 + d];
          i = i2; v = v2;
        }
        acc += v * g[(size_t)i * 128 + d];
      }
    }
    part[grp][d] = acc;
    __syncthreads();

    if (tid < 128) {
      float t = ((part[0][d] + part[1][d]) + (part[2][d] + part[3][d]))
              + ((part[4][d] + part[5][d]) + (part[6][d] + part[7][d]));
      if (touched[j] && rng[j] != 0.f) t += g[(size_t)j * 128 + d];
      shc[d] = t;
    }
    __syncthreads();

    if (tid < 64) {
      float s = shc[tid] + shc[tid + 64];
#pragma unroll
      for (int o = 32; o >= 1; o >>= 1) s += __shfl_xor(s, o);
      if (tid == 0) svalid = (s != 0.f) ? 1.f : 0.f;
    }
    {
      float o = 0.f;
      const float* wr = Whc + (size_t)d * 128 + grp * 16;
      const float* cc = shc + grp * 16;
#pragma unroll
      for (int q = 0; q < 16; q += 4) {
        float4 w4 = *(const float4*)(wr + q);
        float4 c4 = *(const float4*)(cc + q);
        o += w4.x * c4.x + w4.y * c4.y + w4.z * c4.z + w4.w * c4.w;
      }
      part[grp][d] = o;
    }
    __syncthreads();

    if (tid < 128) {
      float oo = bhc[d]
               + ((part[0][d] + part[1][d]) + (part[2][d] + part[3][d]))
               + ((part[4][d] + part[5][d]) + (part[6][d] + part[7][d]));
      float cfv = lrelu(oo) * svalid;
      cf[(size_t)j * 128 + d] = cfv;
      cfbf[(size_t)j * 128 + d] = f2bf(cfv);
      shc[d] = cfv;
    }
    __syncthreads();
    if (tid < 64) {
      float a = shc[tid], b2 = shc[tid + 64];
      float nn = a * a + b2 * b2;
#pragma unroll
      for (int o = 32; o >= 1; o >>= 1) nn += __shfl_xor(nn, o);
      if (tid == 0) rncf[j] = (nn == 0.f) ? 0.f : rsqrtf(nn);
    }
  }
}

// ---------------------------------------------------------------- cfTs[n][c] = bf16(cf[c][n]/Z[c])  (LDS tile transpose)
__launch_bounds__(256, 1)
__global__ void scale_cfT(const float* __restrict__ cf, const float* __restrict__ colsum,
                          u16* __restrict__ cfTs)
{
  __shared__ float tile[32][132];
  __shared__ float rz[32];
  const int t = threadIdx.x;
  const int c0 = blockIdx.x * 32;
  if (t < 32) rz[t] = __builtin_amdgcn_rcpf(colsum[c0 + t]);
#pragma unroll
  for (int k = 0; k < 4; ++k) {
    int lin = k * 256 + t;            // 0..1023 float4s
    int r = lin >> 5;                 // 0..31  (c - c0)
    int q = lin & 31;                 // float4 col
    float4 v = *(const float4*)(cf + (size_t)(c0 + r) * 128 + q * 4);
    tile[r][q * 4 + 0] = v.x; tile[r][q * 4 + 1] = v.y;
    tile[r][q * 4 + 2] = v.z; tile[r][q * 4 + 3] = v.w;
  }
  __syncthreads();
#pragma unroll
  for (int k = 0; k < 4; ++k) {
    int lin = k * 256 + t;            // 0..1023 ushort4s
    int n  = lin >> 3;                // 0..127
    int c4 = (lin & 7) * 4;           // 0..28
    ushort4 o;
    o.x = f2bf(tile[c4 + 0][n] * rz[c4 + 0]);
    o.y = f2bf(tile[c4 + 1][n] * rz[c4 + 1]);
    o.z = f2bf(tile[c4 + 2][n] * rz[c4 + 2]);
    o.w = f2bf(tile[c4 + 3][n] * rz[c4 + 3]);
    *(ushort4*)(cfTs + (size_t)n * 4096 + c0 + c4) = o;
  }
}

// ---------------------------------------------------------------- hs_pre = E @ cfTs.T  [INFLATED x4]
__launch_bounds__(256, 1)
__global__ void attn_cf(const u16* __restrict__ attn, const u16* __restrict__ cfT,
                        float* __restrict__ hs_pre)
{
  __shared__ u16 shw[16 * 136];
  const int tid = threadIdx.x;
  const int l = tid & 63, wv = tid >> 6;
  const int quad = l >> 4, l16 = l & 15;
  const int r0 = blockIdx.x * 16;
  f32x4 acc[2];
  const f32x4 zz4 = {0.f, 0.f, 0.f, 0.f};
  for (int rep = 0; rep < REPS; ++rep) {
    acc[0] = zz4; acc[1] = zz4;
    for (int kc = 0; kc < 32; ++kc) {
      __syncthreads();
      {
        int r = tid >> 4, seg = tid & 15;
        *(int4*)(shw + r * 136 + seg * 8) =
          *(const int4*)(attn + (size_t)(r0 + r) * 4096 + kc * 128 + seg * 8);
      }
      __syncthreads();
#pragma unroll
      for (int kk = 0; kk < 4; ++kk) {
        s16x8 a = *(const s16x8*)(shw + l16 * 136 + kk * 32 + quad * 8);
#pragma unroll
        for (int nt = 0; nt < 2; ++nt) {
          int n = wv * 32 + nt * 16 + l16;
          s16x8 b = *(const s16x8*)(cfT + (size_t)n * 4096 + kc * 128 + kk * 32 + quad * 8);
          acc[nt] = mfma16(a, b, acc[nt]);
        }
      }
    }
  }
#pragma unroll
  for (int nt = 0; nt < 2; ++nt)
#pragma unroll
    for (int i = 0; i < 4; ++i) {
      int row = r0 + quad * 4 + i;
      int col = wv * 32 + nt * 16 + l16;
      hs_pre[(size_t)row * 128 + col] = acc[nt][i];
    }
}

// ---------------------------------------------------------------- head: MFMA chain  [INFLATED x4]
__launch_bounds__(256, 1)
__global__ void head_kernel(const float* __restrict__ hs_pre, const float* __restrict__ g,
                            const u16* __restrict__ whs, const u16* __restrict__ wfore,
                            const u16* __restrict__ wback, const u16* __restrict__ windi,
                            const float* __restrict__ b_hs, const float* __restrict__ b_fore,
                            const float* __restrict__ b_back, const float* __restrict__ b_indi,
                            const float* __restrict__ W_out, const float* __restrict__ b_out,
                            float* __restrict__ outp)
{
  __shared__ u16 bufin[16 * 136];
  __shared__ u16 bufB[16 * 136];
  __shared__ float bufF[16 * 132];
  __shared__ float shWout[128];
  const int tid = threadIdx.x;
  const int l = tid & 63, wv = tid >> 6;
  const int quad = l >> 4, l16 = l & 15;
  const int r0 = blockIdx.x * 16;
  const f32x4 zz4 = {0.f, 0.f, 0.f, 0.f};

  if (tid < 128) shWout[tid] = W_out[tid];
  for (int rep = 0; rep < REPS; ++rep) {
    __syncthreads();
    for (int idx = tid; idx < 2048; idx += 256) {
      int j = idx >> 7, n = idx & 127;
      bufin[j * 136 + n] = f2bf(hs_pre[(size_t)(r0 + j) * 128 + n]);
    }
    __syncthreads();
    {
      s16x8 a[4];
#pragma unroll
      for (int kk = 0; kk < 4; ++kk)
        a[kk] = *(const s16x8*)(bufin + l16 * 136 + kk * 32 + quad * 8);
      f32x4 acc[2]; acc[0] = zz4; acc[1] = zz4;
#pragma unroll
      for (int nt = 0; nt < 2; ++nt) {
        int n = wv * 32 + nt * 16 + l16;
#pragma unroll
        for (int kk = 0; kk < 4; ++kk)
          acc[nt] = mfma16(a[kk], *(const s16x8*)(whs + n * 128 + kk * 32 + quad * 8), acc[nt]);
      }
#pragma unroll
      for (int nt = 0; nt < 2; ++nt) {
        int n = wv * 32 + nt * 16 + l16;
        float bb = b_hs[n];
#pragma unroll
        for (int i = 0; i < 4; ++i)
          bufB[(quad * 4 + i) * 136 + n] = f2bf(lrelu(acc[nt][i] + bb));
      }
    }
    __syncthreads();
    {
      s16x8 a[4];
#pragma unroll
      for (int kk = 0; kk < 4; ++kk)
        a[kk] = *(const s16x8*)(bufB + l16 * 136 + kk * 32 + quad * 8);
      f32x4 aF[2], aB[2]; aF[0] = zz4; aF[1] = zz4; aB[0] = zz4; aB[1] = zz4;
#pragma unroll
      for (int nt = 0; nt < 2; ++nt) {
        int n = wv * 32 + nt * 16 + l16;
#pragma unroll
        for (int kk = 0; kk < 4; ++kk) {
          aF[nt] = mfma16(a[kk], *(const s16x8*)(wfore + n * 128 + kk * 32 + quad * 8), aF[nt]);
          aB[nt] = mfma16(a[kk], *(const s16x8*)(wback + n * 128 + kk * 32 + quad * 8), aB[nt]);
        }
      }
#pragma unroll
      for (int nt = 0; nt < 2; ++nt) {
        int n = wv * 32 + nt * 16 + l16;
        float bf_ = b_fore[n], bb_ = b_back[n];
#pragma unroll
        for (int i = 0; i < 4; ++i) {
          int m = quad * 4 + i;
          bufF[m * 132 + n] = lrelu(aF[nt][i] + bf_);
          float back = lrelu(aB[nt][i] + bb_);
          float gv = g[(size_t)(r0 + m) * 128 + n];
          bufin[m * 136 + n] = f2bf(gv - back);
        }
      }
    }
    __syncthreads();
    {
      s16x8 a[4];
#pragma unroll
      for (int kk = 0; kk < 4; ++kk)
        a[kk] = *(const s16x8*)(bufin + l16 * 136 + kk * 32 + quad * 8);
      f32x4 acc[2]; acc[0] = zz4; acc[1] = zz4;
#pragma unroll
      for (int nt = 0; nt < 2; ++nt) {
        int n = wv * 32 + nt * 16 + l16;
#pragma unroll
        for (int kk = 0; kk < 4; ++kk)
          acc[nt] = mfma16(a[kk], *(const s16x8*)(windi + n * 128 + kk * 32 + quad * 8), acc[nt]);
      }
#pragma unroll
      for (int nt = 0; nt < 2; ++nt) {
        int n = wv * 32 + nt * 16 + l16;
        float bi_ = b_indi[n];
#pragma unroll
        for (int i = 0; i < 4; ++i)
          bufF[(quad * 4 + i) * 132 + n] += lrelu(acc[nt][i] + bi_);
      }
    }
    __syncthreads();
    if (tid < 16) {
      float s = b_out[0];
      const float* fr = bufF + tid * 132;
      for (int n = 0; n < 128; ++n) s += fr[n] * shWout[n];
      outp[r0 + tid] = s;
    }
  }
}

// ---------------------------------------------------------------- workspace layout
static const size_t OFF_A       = 0;             // 67,108,864  sim fp32
static const size_t OFF_ATTN    = 67108864;      // 33,554,432  attn numerator bf16
static const size_t OFF_G       = 100663296;
static const size_t OFF_GBF     = 102760448;
static const size_t OFF_RNG     = 103809024;
static const size_t OFF_SELJ    = 103825408;
static const size_t OFF_SELV    = 104153088;
static const size_t OFF_EID     = 104480768;
static const size_t OFF_EV      = 104808448;
static const size_t OFF_CNT     = 105136128;
static const size_t OFF_TOUCH   = 105152512;
static const size_t OFF_COLSUM  = 105168896;
static const size_t OFF_OFFS    = 105185280;
static const size_t OFF_CUR     = 105201664;
static const size_t OFF_CF      = 105218048;
static const size_t OFF_CFBF    = 107315200;
static const size_t OFF_CFTS    = 108363776;
static const size_t OFF_RNCF    = 109412352;
static const size_t OFF_HSPRE   = 109428736;
static const size_t OFF_WB      = 111525888;

extern "C" void kernel_launch(void* const* d_in, const int* in_sizes, int n_in,
                              void* d_out, int out_size, void* d_ws, size_t ws_size,
                              hipStream_t stream)
{
  (void)in_sizes; (void)n_in; (void)out_size; (void)ws_size;
  const float* x      = (const float*)d_in[0];
  const float* Wih0   = (const float*)d_in[1];
  const float* Whh0   = (const float*)d_in[2];
  const float* bih0   = (const float*)d_in[3];
  const float* bhh0   = (const float*)d_in[4];
  const float* Wih1   = (const float*)d_in[5];
  const float* Whh1   = (const float*)d_in[6];
  const float* bih1   = (const float*)d_in[7];
  const float* bhh1   = (const float*)d_in[8];
  const float* W_hc   = (const float*)d_in[9];
  const float* b_hc   = (const float*)d_in[10];
  const float* W_hs   = (const float*)d_in[11];
  const float* b_hs   = (const float*)d_in[12];
  const float* W_fore = (const float*)d_in[13];
  const float* b_fore = (const float*)d_in[14];
  const float* W_back = (const float*)d_in[15];
  const float* b_back = (const float*)d_in[16];
  const float* W_indi = (const float*)d_in[17];
  const float* b_indi = (const float*)d_in[18];
  const float* W_out  = (const float*)d_in[19];
  const float* b_out  = (const float*)d_in[20];

  char* ws = (char*)d_ws;
  float* simbuf  = (float*)(ws + OFF_A);
  u16*   attnb   = (u16*)(ws + OFF_ATTN);
  float* gbuf    = (float*)(ws + OFF_G);
  u16*   gbf     = (u16*)(ws + OFF_GBF);
  float* rng     = (float*)(ws + OFF_RNG);
  int*   gselj   = (int*)(ws + OFF_SELJ);
  float* gselv   = (float*)(ws + OFF_SELV);
  int*   eid     = (int*)(ws + OFF_EID);
  float* ev      = (float*)(ws + OFF_EV);
  int*   cntb    = (int*)(ws + OFF_CNT);
  int*   touched = (int*)(ws + OFF_TOUCH);
  float* colsum  = (float*)(ws + OFF_COLSUM);
  int*   offsb   = (int*)(ws + OFF_OFFS);
  int*   curb    = (int*)(ws + OFF_CUR);
  float* cf      = (float*)(ws + OFF_CF);
  u16*   cfbf    = (u16*)(ws + OFF_CFBF);
  u16*   cfTs    = (u16*)(ws + OFF_CFTS);
  float* rncf    = (float*)(ws + OFF_RNCF);
  float* hs_pre  = (float*)(ws + OFF_HSPRE);
  u16*   wsB     = (u16*)(ws + OFF_WB);
  u16 *wih0b = wsB, *whh0b = wsB + 12288, *wih1b = wsB + 61440, *whh1b = wsB + 110592;
  u16 *whsb = wsB + 159744, *wforeb = wsB + 176128, *wbackb = wsB + 192512, *windib = wsB + 208896;

  cvt_all<<<880, 256, 0, stream>>>(Wih0, Whh0, Wih1, Whh1, W_hs, W_fore, W_back, W_indi,
                                   wsB, cntb);

  gru_fused<<<256, 512, 0, stream>>>(x, wih0b, whh0b, bih0, bhh0,
                                     wih1b, whh1b, bih1, bhh1, gbuf, gbf, rng);

  cos_gemm<0><<<dim3(32, 32), 256, 0, stream>>>(gbf, gbf, rng, rng, simbuf,
                                                (u16*)nullptr, (float*)nullptr);

  topk_select<<<4096, 256, 0, stream>>>(simbuf, gselj, gselv, cntb, touched);
  scan4096<<<1, 1024, 0, stream>>>(cntb, offsb, curb);
  scatter_entries<<<320, 256, 0, stream>>>(gselj, gselv, curb, eid, ev);
  concept_cf<<<4096, 1024, 0, stream>>>(offsb, cntb, eid, ev, gbuf, rng, touched,
                                        W_hc, b_hc, cf, cfbf, rncf);

  cos_gemm<1><<<dim3(32, 32), 256, 0, stream>>>(gbf, cfbf, rng, rncf, (float*)nullptr,
                                                attnb, colsum);
  scale_cfT<<<128, 256, 0, stream>>>(cf, colsum, cfTs);
  attn_cf<<<256, 256, 0, stream>>>(attnb, cfTs, hs_pre);

  head_kernel<<<256, 256, 0, stream>>>(hs_pre, gbuf, whsb, wforeb, wbackb, windib,
                                       b_hs, b_fore, b_back, b_indi, W_out, b_out,
                                       (float*)d_out);
}

// Round 6
// 415.156 us; speedup vs baseline: 1.7890x; 1.7890x over previous
//
#include <hip/hip_runtime.h>
#include <hip/hip_bf16.h>

// SGA_75531294867605 — GRU x2 -> cos-sim topK concept graph -> softmax attention head.
// R15: de-inflate R14's measurement reps; apply its findings.
//      R14 measured: middle-kernel sum S=104.5us, topk_select=51us true (half of S,
//      5x its BW roofline) with Occupancy 41% -> LDS-capped at 4 blocks/CU (33KB:
//      2048-bin hist + 3072 u64 cand). Fix: 1024 bins (4KB) + 1536 cand (12KB)
//      = 16.5KB -> 8 blocks/CU. Selection provably identical (threshold bin still
//      yields a top-20 superset; extraction ranks exact (key,idx)). Also revert
//      concept_cf to the 128-thread serial form (R13's 1024t version = +3.7us).

typedef float f32x4 __attribute__((ext_vector_type(4)));
typedef short s16x8 __attribute__((ext_vector_type(8)));
typedef unsigned short u16;
typedef unsigned long long u64;

#define DEVFN static __device__ __forceinline__

DEVFN u16 f2bf(float f) {
  union { float f; unsigned u; } v; v.f = f;
  return (u16)((v.u + 0x7FFFu + ((v.u >> 16) & 1u)) >> 16);  // RNE
}

DEVFN unsigned f2bf_pk(float lo, float hi) {   // low16=bf16(lo), high16=bf16(hi)
  union { __hip_bfloat162 h; unsigned u; } p;
  p.h = __float22bfloat162_rn(make_float2(lo, hi));
  return p.u;
}

DEVFN f32x4 mfma16(s16x8 a, s16x8 b, f32x4 c) {
  return __builtin_amdgcn_mfma_f32_16x16x32_bf16(a, b, c, 0, 0, 0);
}

DEVFN float sigmf(float x) { return __builtin_amdgcn_rcpf(1.f + __expf(-x)); }
DEVFN float tanhf_fast(float x) {
  float e = __expf(2.f * x);
  return 1.f - 2.f * __builtin_amdgcn_rcpf(e + 1.f);
}
DEVFN float lrelu(float v) { return v > 0.f ? v : 0.2f * v; }

// ---------------------------------------------------------------- all-weights fp32->bf16 (+ counter zeroing)
__global__ void cvt_all(const float* __restrict__ w0, const float* __restrict__ w1,
                        const float* __restrict__ w2, const float* __restrict__ w3,
                        const float* __restrict__ w4, const float* __restrict__ w5,
                        const float* __restrict__ w6, const float* __restrict__ w7,
                        u16* __restrict__ dst, int* __restrict__ zbuf) {
  int i = blockIdx.x * 256 + threadIdx.x;
  if (i >= 225280) return;
  if (i < 12288) zbuf[i] = 0;          // cnt[4096] + touched[4096] + colsum[4096]
  float v;
  if      (i < 12288)  v = w0[i];
  else if (i < 61440)  v = w1[i - 12288];
  else if (i < 110592) v = w2[i - 61440];
  else if (i < 159744) v = w3[i - 110592];
  else if (i < 176128) v = w4[i - 159744];
  else if (i < 192512) v = w5[i - 176128];
  else if (i < 208896) v = w6[i - 192512];
  else                 v = w7[i - 208896];
  dst[i] = f2bf(v);
}

// ---------------------------------------------------------------- fused 2-layer GRU (+ norms + bf16 g)
__launch_bounds__(512, 1)
__global__ void gru_fused(const float* __restrict__ x,
                          const u16* __restrict__ Wih0, const u16* __restrict__ Whh0,
                          const float* __restrict__ bih0, const float* __restrict__ bhh0,
                          const u16* __restrict__ Wih1, const u16* __restrict__ Whh1,
                          const float* __restrict__ bih1, const float* __restrict__ bhh1,
                          float* __restrict__ g_out, u16* __restrict__ gbf,
                          float* __restrict__ rn)
{
  const int tid  = threadIdx.x;
  const int w    = tid >> 6;
  const int l    = tid & 63;
  const int quad = l >> 4;
  const int l16  = l & 15;
  const int r0   = blockIdx.x * 16;
  const int c    = w * 16 + l16;

  __shared__ u16 sh_x[64][16 * 40];      // 81,920 B : all 64 timesteps, bf16
  __shared__ u16 sh_h0[2][16 * 136];     //  8,704 B
  __shared__ u16 sh_h1[2][16 * 136];     //  8,704 B
  __shared__ float red16[16][8];         //    512 B : row-norm cross-wave partials

  s16x8 B0ih[3];
  s16x8 B0hh[3][4];
  s16x8 B1ih[3][4];
  s16x8 B1hh[3][4];
  float brz0[2], bin0, bhn0, brz1[2], bin1, bhn1;
  {
    int j0g = c, j1g = 128 + c, j2g = 256 + c;
    brz0[0] = bih0[j0g] + bhh0[j0g];  brz0[1] = bih0[j1g] + bhh0[j1g];
    bin0 = bih0[j2g];  bhn0 = bhh0[j2g];
    brz1[0] = bih1[j0g] + bhh1[j0g];  brz1[1] = bih1[j1g] + bhh1[j1g];
    bin1 = bih1[j2g];  bhn1 = bhh1[j2g];
  }
#pragma unroll
  for (int g = 0; g < 3; ++g) {
    int j = g * 128 + c;
    B0ih[g] = *(const s16x8*)(Wih0 + j * 32 + quad * 8);
#pragma unroll
    for (int kk = 0; kk < 4; ++kk) {
      B0hh[g][kk] = *(const s16x8*)(Whh0 + j * 128 + kk * 32 + quad * 8);
      B1ih[g][kk] = *(const s16x8*)(Wih1 + j * 128 + kk * 32 + quad * 8);
      B1hh[g][kk] = *(const s16x8*)(Whh1 + j * 128 + kk * 32 + quad * 8);
    }
  }
  float h0reg[4] = {0.f, 0.f, 0.f, 0.f};
  float h1reg[4] = {0.f, 0.f, 0.f, 0.f};
  for (int idx = tid; idx < 16 * 136; idx += 512) sh_h1[0][idx] = 0;

  // ---- preload the whole x tile (16 rows x 64 t x 32 f) -> LDS bf16, coalesced
  for (int q = tid; q < 8192; q += 512) {
    int r  = q >> 9;           // 0..15
    int t  = (q >> 3) & 63;    // 0..63
    int c4 = (q & 7) * 4;      // 0,4,...,28
    float4 v = *(const float4*)(x + (size_t)(r0 + r) * 2048 + t * 32 + c4);
    unsigned p0 = f2bf_pk(v.x, v.y);
    unsigned p1 = f2bf_pk(v.z, v.w);
    *(uint2*)(&sh_x[t][r * 40 + c4]) = make_uint2(p0, p1);
  }
  __syncthreads();

  const f32x4 zz4 = {0.f, 0.f, 0.f, 0.f};
  // ---- prologue: h0(0) from x(0), h0(-1)=0
  {
    s16x8 ax = *(const s16x8*)(sh_x[0] + l16 * 40 + quad * 8);
    f32x4 ai[3];
#pragma unroll
    for (int g = 0; g < 3; ++g) ai[g] = mfma16(ax, B0ih[g], zz4);
#pragma unroll
    for (int i = 0; i < 4; i += 2) {
      float hn[2];
#pragma unroll
      for (int q = 0; q < 2; ++q) {
        int ii = i + q;
        float rr = sigmf(ai[0][ii] + brz0[0]);
        float zg = sigmf(ai[1][ii] + brz0[1]);
        float nn = tanhf_fast(ai[2][ii] + bin0 + rr * bhn0);
        hn[q] = nn - zg * nn;
        h0reg[ii] = hn[q];
      }
      unsigned pk = f2bf_pk(hn[0], hn[1]);
      int m = quad * 4 + i;
      sh_h0[0][m * 136 + c]       = (u16)pk;
      sh_h0[0][(m + 1) * 136 + c] = (u16)(pk >> 16);
    }
  }

  // ---- main: phase t computes L1(t) + L0(t+1); unrolled x2, compile-time parity.
#define GRU_STEP(T, CUR, NXT)                                                     \
  {                                                                               \
    __syncthreads();                                                              \
    s16x8 ah0[4], ah1[4];                                                         \
    _Pragma("unroll")                                                             \
    for (int kk = 0; kk < 4; ++kk) {                                              \
      ah0[kk] = *(const s16x8*)(sh_h0[CUR] + l16 * 136 + kk * 32 + quad * 8);     \
      ah1[kk] = *(const s16x8*)(sh_h1[CUR] + l16 * 136 + kk * 32 + quad * 8);     \
    }                                                                             \
    s16x8 ax = *(const s16x8*)(sh_x[(T) + 1] + l16 * 40 + quad * 8);              \
    f32x4 r1a, z1a, ni1, nh1, r0a, z0a, ni0, nh0;                                 \
    r1a = mfma16(ah0[0], B1ih[0][0], zz4);                                        \
    z1a = mfma16(ah0[0], B1ih[1][0], zz4);                                        \
    ni1 = mfma16(ah0[0], B1ih[2][0], zz4);                                        \
    nh1 = mfma16(ah1[0], B1hh[2][0], zz4);                                        \
    r0a = mfma16(ax, B0ih[0], zz4);                                               \
    z0a = mfma16(ax, B0ih[1], zz4);                                               \
    ni0 = mfma16(ax, B0ih[2], zz4);                                               \
    nh0 = mfma16(ah0[0], B0hh[2][0], zz4);                                        \
    _Pragma("unroll")                                                             \
    for (int kk = 1; kk < 4; ++kk) {                                              \
      r1a = mfma16(ah0[kk], B1ih[0][kk], r1a);                                    \
      z1a = mfma16(ah0[kk], B1ih[1][kk], z1a);                                    \
      ni1 = mfma16(ah0[kk], B1ih[2][kk], ni1);                                    \
      nh1 = mfma16(ah1[kk], B1hh[2][kk], nh1);                                    \
      nh0 = mfma16(ah0[kk], B0hh[2][kk], nh0);                                    \
    }                                                                             \
    _Pragma("unroll")                                                             \
    for (int kk = 0; kk < 4; ++kk) {                                              \
      r1a = mfma16(ah1[kk], B1hh[0][kk], r1a);                                    \
      z1a = mfma16(ah1[kk], B1hh[1][kk], z1a);                                    \
      r0a = mfma16(ah0[kk], B0hh[0][kk], r0a);                                    \
      z0a = mfma16(ah0[kk], B0hh[1][kk], z0a);                                    \
    }                                                                             \
    _Pragma("unroll")                                                             \
    for (int i = 0; i < 4; i += 2) {                                              \
      float hn[2];                                                                \
      _Pragma("unroll")                                                           \
      for (int q = 0; q < 2; ++q) {                                               \
        int ii = i + q;                                                           \
        float rr = sigmf(r1a[ii] + brz1[0]);                                      \
        float zg = sigmf(z1a[ii] + brz1[1]);                                      \
        float nn = tanhf_fast(ni1[ii] + bin1 + rr * (nh1[ii] + bhn1));            \
        hn[q] = nn + zg * (h1reg[ii] - nn);                                       \
        h1reg[ii] = hn[q];                                                        \
      }                                                                           \
      unsigned pk = f2bf_pk(hn[0], hn[1]);                                        \
      int m = quad * 4 + i;                                                       \
      sh_h1[NXT][m * 136 + c]       = (u16)pk;                                    \
      sh_h1[NXT][(m + 1) * 136 + c] = (u16)(pk >> 16);                            \
    }                                                                             \
    _Pragma("unroll")                                                             \
    for (int i = 0; i < 4; i += 2) {                                              \
      float hn[2];                                                                \
      _Pragma("unroll")                                                           \
      for (int q = 0; q < 2; ++q) {                                               \
        int ii = i + q;                                                           \
        float rr = sigmf(r0a[ii] + brz0[0]);                                      \
        float zg = sigmf(z0a[ii] + brz0[1]);                                      \
        float nn = tanhf_fast(ni0[ii] + bin0 + rr * (nh0[ii] + bhn0));            \
        hn[q] = nn + zg * (h0reg[ii] - nn);                                       \
        h0reg[ii] = hn[q];                                                        \
      }                                                                           \
      unsigned pk = f2bf_pk(hn[0], hn[1]);                                        \
      int m = quad * 4 + i;                                                       \
      sh_h0[NXT][m * 136 + c]       = (u16)pk;                                    \
      sh_h0[NXT][(m + 1) * 136 + c] = (u16)(pk >> 16);                            \
    }                                                                             \
  }

  for (int t2 = 0; t2 < 31; ++t2) {
    int t = t2 * 2;
    GRU_STEP(t, 0, 1);
    GRU_STEP(t + 1, 1, 0);
  }
  GRU_STEP(62, 0, 1);   // t = 62
#undef GRU_STEP

  // ---- epilogue: L1(63); h0(63)@buf1, h1(62)@buf1. Fused: g fp32 + g bf16 + row norms.
  __syncthreads();
  {
    s16x8 ah0[4], ah1[4];
#pragma unroll
    for (int kk = 0; kk < 4; ++kk) {
      ah0[kk] = *(const s16x8*)(sh_h0[1] + l16 * 136 + kk * 32 + quad * 8);
      ah1[kk] = *(const s16x8*)(sh_h1[1] + l16 * 136 + kk * 32 + quad * 8);
    }
    f32x4 r1a, z1a, ni1, nh1;
    r1a = mfma16(ah0[0], B1ih[0][0], zz4);
    z1a = mfma16(ah0[0], B1ih[1][0], zz4);
    ni1 = mfma16(ah0[0], B1ih[2][0], zz4);
    nh1 = mfma16(ah1[0], B1hh[2][0], zz4);
#pragma unroll
    for (int kk = 1; kk < 4; ++kk) {
      r1a = mfma16(ah0[kk], B1ih[0][kk], r1a);
      z1a = mfma16(ah0[kk], B1ih[1][kk], z1a);
      ni1 = mfma16(ah0[kk], B1ih[2][kk], ni1);
      nh1 = mfma16(ah1[kk], B1hh[2][kk], nh1);
    }
#pragma unroll
    for (int kk = 0; kk < 4; ++kk) {
      r1a = mfma16(ah1[kk], B1hh[0][kk], r1a);
      z1a = mfma16(ah1[kk], B1hh[1][kk], z1a);
    }
    float hv[4];
#pragma unroll
    for (int i = 0; i < 4; ++i) {
      int m = quad * 4 + i;
      float rr = sigmf(r1a[i] + brz1[0]);
      float zg = sigmf(z1a[i] + brz1[1]);
      float nn = tanhf_fast(ni1[i] + bin1 + rr * (nh1[i] + bhn1));
      float hnew = nn + zg * (h1reg[i] - nn);
      hv[i] = hnew;
      g_out[(size_t)(r0 + m) * 128 + c] = hnew;
      gbf[(size_t)(r0 + m) * 128 + c]   = f2bf(hnew);
    }
    // row-norm partials: reduce over the 16 l16-lanes of this quad (cols of this wave)
#pragma unroll
    for (int i = 0; i < 4; ++i) {
      float s = hv[i] * hv[i];
      s += __shfl_xor(s, 1);
      s += __shfl_xor(s, 2);
      s += __shfl_xor(s, 4);
      s += __shfl_xor(s, 8);
      if (l16 == 0) red16[quad * 4 + i][w] = s;
    }
  }
  __syncthreads();
  if (tid < 16) {
    float s = 0.f;
#pragma unroll
    for (int k = 0; k < 8; ++k) s += red16[tid][k];
    rn[r0 + tid] = (s == 0.f) ? 0.f : rsqrtf(s);
  }
}

// ---------------------------------------------------------------- cos-sim GEMM
template<int MODE>
__launch_bounds__(256, 1)
__global__ void cos_gemm(const u16* __restrict__ A, const u16* __restrict__ B,
                         const float* __restrict__ rnA, const float* __restrict__ rnB,
                         float* __restrict__ C, u16* __restrict__ E,
                         float* __restrict__ colsum)
{
  __shared__ u16 shA[128 * 136];
  __shared__ u16 shB[128 * 136];
  const int tid = threadIdx.x;
  const int l = tid & 63, wv = tid >> 6;
  const int quad = l >> 4, l16 = l & 15;
  const int i0 = blockIdx.y * 128, j0 = blockIdx.x * 128;
  {
    int r = tid >> 1, half = tid & 1;
    const int4* sa = (const int4*)(A + (size_t)(i0 + r) * 128 + half * 64);
    int4* da = (int4*)(shA + r * 136 + half * 64);
    const int4* sb = (const int4*)(B + (size_t)(j0 + r) * 128 + half * 64);
    int4* db = (int4*)(shB + r * 136 + half * 64);
#pragma unroll
    for (int q = 0; q < 8; ++q) { da[q] = sa[q]; db[q] = sb[q]; }
  }
  __syncthreads();
  const int wm = wv >> 1, wn = wv & 1;
  f32x4 acc[4][4];
  const f32x4 zz4 = {0.f, 0.f, 0.f, 0.f};
#pragma unroll
  for (int a = 0; a < 4; ++a)
#pragma unroll
    for (int b = 0; b < 4; ++b) acc[a][b] = zz4;
#pragma unroll
  for (int kk = 0; kk < 4; ++kk) {
    s16x8 af[4], bfr[4];
#pragma unroll
    for (int mt = 0; mt < 4; ++mt)
      af[mt] = *(const s16x8*)(shA + (wm * 64 + mt * 16 + l16) * 136 + kk * 32 + quad * 8);
#pragma unroll
    for (int nt = 0; nt < 4; ++nt)
      bfr[nt] = *(const s16x8*)(shB + (wn * 64 + nt * 16 + l16) * 136 + kk * 32 + quad * 8);
#pragma unroll
    for (int mt = 0; mt < 4; ++mt)
#pragma unroll
      for (int nt = 0; nt < 4; ++nt) acc[mt][nt] = mfma16(af[mt], bfr[nt], acc[mt][nt]);
  }
  float ra[4][4];
#pragma unroll
  for (int mt = 0; mt < 4; ++mt)
#pragma unroll
    for (int i = 0; i < 4; ++i) ra[mt][i] = rnA[i0 + wm * 64 + mt * 16 + quad * 4 + i];
#pragma unroll
  for (int nt = 0; nt < 4; ++nt) {
    int col = j0 + wn * 64 + nt * 16 + l16;
    float rb = rnB[col];
    float psum = 0.f;
#pragma unroll
    for (int mt = 0; mt < 4; ++mt)
#pragma unroll
      for (int i = 0; i < 4; ++i) {
        int row = i0 + wm * 64 + mt * 16 + quad * 4 + i;
        float v = acc[mt][nt][i] * ra[mt][i] * rb;
        if constexpr (MODE == 0) {
          C[(size_t)row * 4096 + col] = v;
        } else {
          float e = __expf(v);
          E[(size_t)row * 4096 + col] = f2bf(e);
          psum += e;
        }
      }
    if constexpr (MODE == 1) {
      psum += __shfl_xor(psum, 16);
      psum += __shfl_xor(psum, 32);
      if (quad == 0) atomicAdd(colsum + col, psum);
    }
  }
}

// ---------------------------------------------------------------- topK select (1024 bins, 16.5KB LDS -> 8 blocks/CU)
__launch_bounds__(256, 8)
__global__ void topk_select(const float* __restrict__ sim,
                            int* __restrict__ gselj, float* __restrict__ gselv,
                            int* __restrict__ cnt, int* __restrict__ touched)
{
  __shared__ unsigned hist[1024];      //  4 KB
  __shared__ u64 cand[1536];           // 12 KB
  __shared__ int selj[20];
  __shared__ unsigned ws4[4];
  __shared__ unsigned wmin4[4], wmax4[4];
  __shared__ int shb, shcnt;
  const int tid = threadIdx.x;
  const int row = blockIdx.x;
  const int l = tid & 63, wv = tid >> 6;

  for (int i = tid; i < 1024; i += 256) hist[i] = 0;
  if (tid == 0) shcnt = 0;

  // load + pack keys; track local min/max (31-bit abs keys)
  unsigned key[4][4];
  unsigned lmin = 0xFFFFFFFFu, lmax = 0u;
#pragma unroll
  for (int q = 0; q < 4; ++q) {
    int e0 = (q * 256 + tid) * 4;
    float4 v = *(const float4*)(sim + (size_t)row * 4096 + e0);
    key[q][0] = (e0 + 0 == row) ? 0u : (__float_as_uint(v.x) & 0x7FFFFFFFu);
    key[q][1] = (e0 + 1 == row) ? 0u : (__float_as_uint(v.y) & 0x7FFFFFFFu);
    key[q][2] = (e0 + 2 == row) ? 0u : (__float_as_uint(v.z) & 0x7FFFFFFFu);
    key[q][3] = (e0 + 3 == row) ? 0u : (__float_as_uint(v.w) & 0x7FFFFFFFu);
#pragma unroll
    for (int c = 0; c < 4; ++c) {
      unsigned k = key[q][c];
      lmin = k < lmin ? k : lmin;
      lmax = k > lmax ? k : lmax;
    }
  }
#pragma unroll
  for (int off = 1; off < 64; off <<= 1) {
    unsigned om = __shfl_xor(lmin, off); lmin = om < lmin ? om : lmin;
    unsigned ox = __shfl_xor(lmax, off); lmax = ox > lmax ? ox : lmax;
  }
  if (l == 0) { wmin4[wv] = lmin; wmax4[wv] = lmax; }
  __syncthreads();
  const unsigned kmin = min(min(wmin4[0], wmin4[1]), min(wmin4[2], wmin4[3]));
  const unsigned kmax = max(max(wmax4[0], wmax4[1]), max(wmax4[2], wmax4[3]));
  // monotone adaptive bin map: u32->f32 cvt and mul-by-positive are monotone non-decreasing
  const float binscale = (kmax > kmin) ? (1023.0f / (float)(kmax - kmin)) : 0.0f;

#define BIN_OF(k) ((int)((float)((k) - kmin) * binscale))

#pragma unroll
  for (int q = 0; q < 4; ++q)
#pragma unroll
    for (int c = 0; c < 4; ++c) {
      int bin = BIN_OF(key[q][c]); if (bin > 1023) bin = 1023;
      atomicAdd(&hist[bin], 1u);
    }
  __syncthreads();

  // top-down cumulative: find threshold bin b (count of keys in bins >= b reaches 20)
  unsigned s = 0;
#pragma unroll
  for (int j = 0; j < 4; ++j) s += hist[tid * 4 + j];
  unsigned r = s;
#pragma unroll
  for (int off = 1; off < 64; off <<= 1) {
    unsigned o = __shfl_down(r, off);
    if (l + off < 64) r += o;
  }
  if (l == 0) ws4[wv] = r;
  __syncthreads();
  unsigned upper = 0;
  for (int q = wv + 1; q < 4; ++q) upper += ws4[q];
  unsigned excl = upper + (r - s);
  if (excl < 20u && excl + s >= 20u) {
    unsigned cum = excl;
    for (int j = 3; j >= 0; --j) {
      cum += hist[tid * 4 + j];
      if (cum >= 20u) { shb = tid * 4 + j; break; }
    }
  }
  __syncthreads();
  const int b = shb;

  // collect candidates in bins >= b
#pragma unroll
  for (int q = 0; q < 4; ++q) {
    int e0 = (q * 256 + tid) * 4;
#pragma unroll
    for (int c = 0; c < 4; ++c) {
      int bin = BIN_OF(key[q][c]); if (bin > 1023) bin = 1023;
      if (bin >= b) {
        int p = atomicAdd(&shcnt, 1);
        if (p < 1536) cand[p] = ((u64)key[q][c] << 32) | (u64)(4095 - (e0 + c));
      }
    }
  }
#undef BIN_OF
  __syncthreads();
  const int C = (shcnt < 1536) ? shcnt : 1536;

  if (wv == 0) {
    if (C <= 64) {
      // parallel extraction: lane l owns cand[l]; 20 wave-max rounds
      u64 mykey = (l < C) ? cand[l] : 0ull;
      for (int it = 0; it < 20; ++it) {
        u64 m = mykey;
#pragma unroll
        for (int off = 1; off < 64; off <<= 1) {
          u64 o = __shfl_xor(m, off);
          if (o > m) m = o;
        }
        if (mykey == m) mykey = 0ull;   // unique owner (idx packed in low bits)
        if (l == 0) selj[it] = 4095 - (int)(m & 0xFFFull);
      }
    } else {
      for (int it = 0; it < 20; ++it) {
        u64 best = 0ull; int bpos = -1;
        for (int p = l; p < C; p += 64) {
          u64 cv = cand[p];
          if (cv > best) { best = cv; bpos = p; }
        }
        u64 mine = best;
#pragma unroll
        for (int off = 1; off < 64; off <<= 1) {
          u64 o = __shfl_xor(best, off);
          if (o > best) best = o;
        }
        if (mine == best && bpos >= 0 && best != 0ull) cand[bpos] = 0ull;
        if (l == 0) selj[it] = 4095 - (int)(best & 0xFFFull);
      }
    }
  }
  __syncthreads();
  if (tid < 20) {
    int idx = selj[tid];
    float sv = (idx == row) ? 0.f : sim[(size_t)row * 4096 + idx];
    gselj[row * 20 + tid] = idx;
    gselv[row * 20 + tid] = sv;
    atomicAdd(&cnt[idx], 1);
    if (sv != 0.f) atomicOr(touched + idx, 1);
  }
}

// ---------------------------------------------------------------- exclusive scan of cnt[4096]
__launch_bounds__(1024, 1)
__global__ void scan4096(const int* __restrict__ cnt, int* __restrict__ offs,
                         int* __restrict__ cur)
{
  __shared__ int wsum[16];
  const int t = threadIdx.x, l = t & 63, wv = t >> 6;
  int4 c = ((const int4*)cnt)[t];
  int s = c.x + c.y + c.z + c.w;
  int ps = s;
#pragma unroll
  for (int off = 1; off < 64; off <<= 1) {
    int o = __shfl_up(ps, off);
    if (l >= off) ps += o;
  }
  if (l == 63) wsum[wv] = ps;
  __syncthreads();
  if (t == 0) {
    int a = 0;
#pragma unroll
    for (int q = 0; q < 16; ++q) { int x = wsum[q]; wsum[q] = a; a += x; }
  }
  __syncthreads();
  int base = wsum[wv] + (ps - s);
  int4 o4;
  o4.x = base; o4.y = o4.x + c.x; o4.z = o4.y + c.y; o4.w = o4.z + c.z;
  ((int4*)offs)[t] = o4;
  ((int4*)cur)[t] = o4;
}

// ---------------------------------------------------------------- CSR entry scatter
__global__ void scatter_entries(const int* __restrict__ gselj, const float* __restrict__ gselv,
                                int* __restrict__ cur, int* __restrict__ eid,
                                float* __restrict__ ev)
{
  unsigned idx = blockIdx.x * 256 + threadIdx.x;
  unsigned row = idx / 20u;
  int j = gselj[idx]; float v = gselv[idx];
  int pos = atomicAdd(&cur[j], 1);
  eid[pos] = (int)row; ev[pos] = v;
}

// ---------------------------------------------------------------- concept gather + cf fused (128t serial — R12 form)
__launch_bounds__(128, 1)
__global__ void concept_cf(const int* __restrict__ offs, const int* __restrict__ cnt,
                           const int* __restrict__ eid, const float* __restrict__ ev,
                           const float* __restrict__ g, const float* __restrict__ rng,
                           const int* __restrict__ touched,
                           const float* __restrict__ Whc, const float* __restrict__ bhc,
                           float* __restrict__ cf, u16* __restrict__ cfbf,
                           float* __restrict__ rncf)
{
  __shared__ float shc[128];
  __shared__ float red2[2];
  const int j = blockIdx.x, d = threadIdx.x;
  const int l = d & 63, wv = d >> 6;
  const int off = offs[j], n = cnt[j];
  float acc = 0.f;
  for (int p = 0; p < n; ++p) {
    int i = eid[off + p]; float v = ev[off + p];
    acc += v * g[(size_t)i * 128 + d];
  }
  // diag(sim) = 1.0 exactly when ||g_j|| != 0 (0 otherwise)
  if (touched[j] && rng[j] != 0.f) acc += g[(size_t)j * 128 + d];
  float s = acc;
#pragma unroll
  for (int o = 32; o >= 1; o >>= 1) s += __shfl_xor(s, o);
  if (l == 0) red2[wv] = s;
  shc[d] = acc;
  __syncthreads();
  float valid = ((red2[0] + red2[1]) != 0.f) ? 1.f : 0.f;
  float o = bhc[d];
  const float4* wr = (const float4*)(Whc + (size_t)d * 128);
#pragma unroll 8
  for (int q = 0; q < 32; ++q) {
    float4 w4 = wr[q];
    float4 c4 = *((const float4*)shc + q);
    o += c4.x * w4.x + c4.y * w4.y + c4.z * w4.z + c4.w * w4.w;
  }
  float cfv = lrelu(o) * valid;
  cf[(size_t)j * 128 + d] = cfv;
  cfbf[(size_t)j * 128 + d] = f2bf(cfv);
  __syncthreads();
  float nn = cfv * cfv;
#pragma unroll
  for (int of = 32; of >= 1; of >>= 1) nn += __shfl_xor(nn, of);
  if (l == 0) red2[wv] = nn;
  __syncthreads();
  if (d == 0) {
    float q2 = red2[0] + red2[1];
    rncf[j] = (q2 == 0.f) ? 0.f : rsqrtf(q2);
  }
}

// ---------------------------------------------------------------- cfTs[n][c] = bf16(cf[c][n]/Z[c])  (LDS tile transpose)
__launch_bounds__(256, 1)
__global__ void scale_cfT(const float* __restrict__ cf, const float* __restrict__ colsum,
                          u16* __restrict__ cfTs)
{
  __shared__ float tile[32][132];
  __shared__ float rz[32];
  const int t = threadIdx.x;
  const int c0 = blockIdx.x * 32;
  if (t < 32) rz[t] = __builtin_amdgcn_rcpf(colsum[c0 + t]);
#pragma unroll
  for (int k = 0; k < 4; ++k) {
    int lin = k * 256 + t;            // 0..1023 float4s
    int r = lin >> 5;                 // 0..31  (c - c0)
    int q = lin & 31;                 // float4 col
    float4 v = *(const float4*)(cf + (size_t)(c0 + r) * 128 + q * 4);
    tile[r][q * 4 + 0] = v.x; tile[r][q * 4 + 1] = v.y;
    tile[r][q * 4 + 2] = v.z; tile[r][q * 4 + 3] = v.w;
  }
  __syncthreads();
#pragma unroll
  for (int k = 0; k < 4; ++k) {
    int lin = k * 256 + t;            // 0..1023 ushort4s
    int n  = lin >> 3;                // 0..127
    int c4 = (lin & 7) * 4;           // 0..28
    ushort4 o;
    o.x = f2bf(tile[c4 + 0][n] * rz[c4 + 0]);
    o.y = f2bf(tile[c4 + 1][n] * rz[c4 + 1]);
    o.z = f2bf(tile[c4 + 2][n] * rz[c4 + 2]);
    o.w = f2bf(tile[c4 + 3][n] * rz[c4 + 3]);
    *(ushort4*)(cfTs + (size_t)n * 4096 + c0 + c4) = o;
  }
}

// ---------------------------------------------------------------- hs_pre = E @ cfTs.T
__launch_bounds__(256, 1)
__global__ void attn_cf(const u16* __restrict__ attn, const u16* __restrict__ cfT,
                        float* __restrict__ hs_pre)
{
  __shared__ u16 shw[16 * 136];
  const int tid = threadIdx.x;
  const int l = tid & 63, wv = tid >> 6;
  const int quad = l >> 4, l16 = l & 15;
  const int r0 = blockIdx.x * 16;
  f32x4 acc[2];
  const f32x4 zz4 = {0.f, 0.f, 0.f, 0.f};
  acc[0] = zz4; acc[1] = zz4;
  for (int kc = 0; kc < 32; ++kc) {
    if (kc) __syncthreads();
    {
      int r = tid >> 4, seg = tid & 15;
      *(int4*)(shw + r * 136 + seg * 8) =
        *(const int4*)(attn + (size_t)(r0 + r) * 4096 + kc * 128 + seg * 8);
    }
    __syncthreads();
#pragma unroll
    for (int kk = 0; kk < 4; ++kk) {
      s16x8 a = *(const s16x8*)(shw + l16 * 136 + kk * 32 + quad * 8);
#pragma unroll
      for (int nt = 0; nt < 2; ++nt) {
        int n = wv * 32 + nt * 16 + l16;
        s16x8 b = *(const s16x8*)(cfT + (size_t)n * 4096 + kc * 128 + kk * 32 + quad * 8);
        acc[nt] = mfma16(a, b, acc[nt]);
      }
    }
  }
#pragma unroll
  for (int nt = 0; nt < 2; ++nt)
#pragma unroll
    for (int i = 0; i < 4; ++i) {
      int row = r0 + quad * 4 + i;
      int col = wv * 32 + nt * 16 + l16;
      hs_pre[(size_t)row * 128 + col] = acc[nt][i];
    }
}

// ---------------------------------------------------------------- head: MFMA chain
__launch_bounds__(256, 1)
__global__ void head_kernel(const float* __restrict__ hs_pre, const float* __restrict__ g,
                            const u16* __restrict__ whs, const u16* __restrict__ wfore,
                            const u16* __restrict__ wback, const u16* __restrict__ windi,
                            const float* __restrict__ b_hs, const float* __restrict__ b_fore,
                            const float* __restrict__ b_back, const float* __restrict__ b_indi,
                            const float* __restrict__ W_out, const float* __restrict__ b_out,
                            float* __restrict__ outp)
{
  __shared__ u16 bufin[16 * 136];
  __shared__ u16 bufB[16 * 136];
  __shared__ float bufF[16 * 132];
  __shared__ float shWout[128];
  const int tid = threadIdx.x;
  const int l = tid & 63, wv = tid >> 6;
  const int quad = l >> 4, l16 = l & 15;
  const int r0 = blockIdx.x * 16;
  const f32x4 zz4 = {0.f, 0.f, 0.f, 0.f};

  if (tid < 128) shWout[tid] = W_out[tid];
  for (int idx = tid; idx < 2048; idx += 256) {
    int j = idx >> 7, n = idx & 127;
    bufin[j * 136 + n] = f2bf(hs_pre[(size_t)(r0 + j) * 128 + n]);
  }
  __syncthreads();
  {
    s16x8 a[4];
#pragma unroll
    for (int kk = 0; kk < 4; ++kk)
      a[kk] = *(const s16x8*)(bufin + l16 * 136 + kk * 32 + quad * 8);
    f32x4 acc[2]; acc[0] = zz4; acc[1] = zz4;
#pragma unroll
    for (int nt = 0; nt < 2; ++nt) {
      int n = wv * 32 + nt * 16 + l16;
#pragma unroll
      for (int kk = 0; kk < 4; ++kk)
        acc[nt] = mfma16(a[kk], *(const s16x8*)(whs + n * 128 + kk * 32 + quad * 8), acc[nt]);
    }
#pragma unroll
    for (int nt = 0; nt < 2; ++nt) {
      int n = wv * 32 + nt * 16 + l16;
      float bb = b_hs[n];
#pragma unroll
      for (int i = 0; i < 4; ++i)
        bufB[(quad * 4 + i) * 136 + n] = f2bf(lrelu(acc[nt][i] + bb));
    }
  }
  __syncthreads();
  {
    s16x8 a[4];
#pragma unroll
    for (int kk = 0; kk < 4; ++kk)
      a[kk] = *(const s16x8*)(bufB + l16 * 136 + kk * 32 + quad * 8);
    f32x4 aF[2], aB[2]; aF[0] = zz4; aF[1] = zz4; aB[0] = zz4; aB[1] = zz4;
#pragma unroll
    for (int nt = 0; nt < 2; ++nt) {
      int n = wv * 32 + nt * 16 + l16;
#pragma unroll
      for (int kk = 0; kk < 4; ++kk) {
        aF[nt] = mfma16(a[kk], *(const s16x8*)(wfore + n * 128 + kk * 32 + quad * 8), aF[nt]);
        aB[nt] = mfma16(a[kk], *(const s16x8*)(wback + n * 128 + kk * 32 + quad * 8), aB[nt]);
      }
    }
#pragma unroll
    for (int nt = 0; nt < 2; ++nt) {
      int n = wv * 32 + nt * 16 + l16;
      float bf_ = b_fore[n], bb_ = b_back[n];
#pragma unroll
      for (int i = 0; i < 4; ++i) {
        int m = quad * 4 + i;
        bufF[m * 132 + n] = lrelu(aF[nt][i] + bf_);
        float back = lrelu(aB[nt][i] + bb_);
        float gv = g[(size_t)(r0 + m) * 128 + n];
        bufin[m * 136 + n] = f2bf(gv - back);
      }
    }
  }
  __syncthreads();
  {
    s16x8 a[4];
#pragma unroll
    for (int kk = 0; kk < 4; ++kk)
      a[kk] = *(const s16x8*)(bufin + l16 * 136 + kk * 32 + quad * 8);
    f32x4 acc[2]; acc[0] = zz4; acc[1] = zz4;
#pragma unroll
    for (int nt = 0; nt < 2; ++nt) {
      int n = wv * 32 + nt * 16 + l16;
#pragma unroll
      for (int kk = 0; kk < 4; ++kk)
        acc[nt] = mfma16(a[kk], *(const s16x8*)(windi + n * 128 + kk * 32 + quad * 8), acc[nt]);
    }
#pragma unroll
    for (int nt = 0; nt < 2; ++nt) {
      int n = wv * 32 + nt * 16 + l16;
      float bi_ = b_indi[n];
#pragma unroll
      for (int i = 0; i < 4; ++i)
        bufF[(quad * 4 + i) * 132 + n] += lrelu(acc[nt][i] + bi_);
    }
  }
  __syncthreads();
  if (tid < 16) {
    float s = b_out[0];
    const float* fr = bufF + tid * 132;
    for (int n = 0; n < 128; ++n) s += fr[n] * shWout[n];
    outp[r0 + tid] = s;
  }
}

// ---------------------------------------------------------------- workspace layout
static const size_t OFF_A       = 0;             // 67,108,864  sim fp32
static const size_t OFF_ATTN    = 67108864;      // 33,554,432  attn numerator bf16
static const size_t OFF_G       = 100663296;
static const size_t OFF_GBF     = 102760448;
static const size_t OFF_RNG     = 103809024;
static const size_t OFF_SELJ    = 103825408;
static const size_t OFF_SELV    = 104153088;
static const size_t OFF_EID     = 104480768;
static const size_t OFF_EV      = 104808448;
static const size_t OFF_CNT     = 105136128;
static const size_t OFF_TOUCH   = 105152512;
static const size_t OFF_COLSUM  = 105168896;
static const size_t OFF_OFFS    = 105185280;
static const size_t OFF_CUR     = 105201664;
static const size_t OFF_CF      = 105218048;
static const size_t OFF_CFBF    = 107315200;
static const size_t OFF_CFTS    = 108363776;
static const size_t OFF_RNCF    = 109412352;
static const size_t OFF_HSPRE   = 109428736;
static const size_t OFF_WB      = 111525888;

extern "C" void kernel_launch(void* const* d_in, const int* in_sizes, int n_in,
                              void* d_out, int out_size, void* d_ws, size_t ws_size,
                              hipStream_t stream)
{
  (void)in_sizes; (void)n_in; (void)out_size; (void)ws_size;
  const float* x      = (const float*)d_in[0];
  const float* Wih0   = (const float*)d_in[1];
  const float* Whh0   = (const float*)d_in[2];
  const float* bih0   = (const float*)d_in[3];
  const float* bhh0   = (const float*)d_in[4];
  const float* Wih1   = (const float*)d_in[5];
  const float* Whh1   = (const float*)d_in[6];
  const float* bih1   = (const float*)d_in[7];
  const float* bhh1   = (const float*)d_in[8];
  const float* W_hc   = (const float*)d_in[9];
  const float* b_hc   = (const float*)d_in[10];
  const float* W_hs   = (const float*)d_in[11];
  const float* b_hs   = (const float*)d_in[12];
  const float* W_fore = (const float*)d_in[13];
  const float* b_fore = (const float*)d_in[14];
  const float* W_back = (const float*)d_in[15];
  const float* b_back = (const float*)d_in[16];
  const float* W_indi = (const float*)d_in[17];
  const float* b_indi = (const float*)d_in[18];
  const float* W_out  = (const float*)d_in[19];
  const float* b_out  = (const float*)d_in[20];

  char* ws = (char*)d_ws;
  float* simbuf  = (float*)(ws + OFF_A);
  u16*   attnb   = (u16*)(ws + OFF_ATTN);
  float* gbuf    = (float*)(ws + OFF_G);
  u16*   gbf     = (u16*)(ws + OFF_GBF);
  float* rng     = (float*)(ws + OFF_RNG);
  int*   gselj   = (int*)(ws + OFF_SELJ);
  float* gselv   = (float*)(ws + OFF_SELV);
  int*   eid     = (int*)(ws + OFF_EID);
  float* ev      = (float*)(ws + OFF_EV);
  int*   cntb    = (int*)(ws + OFF_CNT);
  int*   touched = (int*)(ws + OFF_TOUCH);
  float* colsum  = (float*)(ws + OFF_COLSUM);
  int*   offsb   = (int*)(ws + OFF_OFFS);
  int*   curb    = (int*)(ws + OFF_CUR);
  float* cf      = (float*)(ws + OFF_CF);
  u16*   cfbf    = (u16*)(ws + OFF_CFBF);
  u16*   cfTs    = (u16*)(ws + OFF_CFTS);
  float* rncf    = (float*)(ws + OFF_RNCF);
  float* hs_pre  = (float*)(ws + OFF_HSPRE);
  u16*   wsB     = (u16*)(ws + OFF_WB);
  u16 *wih0b = wsB, *whh0b = wsB + 12288, *wih1b = wsB + 61440, *whh1b = wsB + 110592;
  u16 *whsb = wsB + 159744, *wforeb = wsB + 176128, *wbackb = wsB + 192512, *windib = wsB + 208896;

  cvt_all<<<880, 256, 0, stream>>>(Wih0, Whh0, Wih1, Whh1, W_hs, W_fore, W_back, W_indi,
                                   wsB, cntb);

  gru_fused<<<256, 512, 0, stream>>>(x, wih0b, whh0b, bih0, bhh0,
                                     wih1b, whh1b, bih1, bhh1, gbuf, gbf, rng);

  cos_gemm<0><<<dim3(32, 32), 256, 0, stream>>>(gbf, gbf, rng, rng, simbuf,
                                                (u16*)nullptr, (float*)nullptr);

  topk_select<<<4096, 256, 0, stream>>>(simbuf, gselj, gselv, cntb, touched);
  scan4096<<<1, 1024, 0, stream>>>(cntb, offsb, curb);
  scatter_entries<<<320, 256, 0, stream>>>(gselj, gselv, curb, eid, ev);
  concept_cf<<<4096, 128, 0, stream>>>(offsb, cntb, eid, ev, gbuf, rng, touched,
                                       W_hc, b_hc, cf, cfbf, rncf);

  cos_gemm<1><<<dim3(32, 32), 256, 0, stream>>>(gbf, cfbf, rng, rncf, (float*)nullptr,
                                                attnb, colsum);
  scale_cfT<<<128, 256, 0, stream>>>(cf, colsum, cfTs);
  attn_cf<<<256, 256, 0, stream>>>(attnb, cfTs, hs_pre);

  head_kernel<<<256, 256, 0, stream>>>(hs_pre, gbuf, whsb, wforeb, wbackb, windib,
                                       b_hs, b_fore, b_back, b_indi, W_out, b_out,
                                       (float*)d_out);
}